// Round 12
// baseline (294.973 us; speedup 1.0000x reference)
//
#include <hip/hip_runtime.h>

#define DIM     256
#define HW      1024
#define N_ROWS  65536
#define NT      256
#define QBM     64
#define NBLK    1024
#define MARGIN  0.0625f

#define OUT_Q_OFF    16777216
#define OUT_LOSS_OFF 16842752

// ws: floats [0,512) c2 ; [512,1536) dist partials(1024) ; [1536,2560) x2 partials(1024)
// int [3072] flag count ; ints [4096, 69632) flagged-row list
// bytes [524288, 1048576) lut bf16 hi/lo fragment-linear
#define WS_DIST   512
#define WS_X2     1536
#define WS_CNT_I  3072
#define WS_LIST_I 4096
#define WS_LUTBF_B 524288

#define VQ_LDS 69632   // 64KB A + red arrays

typedef __attribute__((ext_vector_type(8))) short short8v;
typedef __attribute__((ext_vector_type(4))) float floatx4;

__device__ __forceinline__ unsigned short bf16_rne(float f) {
    unsigned int u = __float_as_uint(f);
    u += 0x7fffu + ((u >> 16) & 1u);
    return (unsigned short)(u >> 16);
}
__device__ __forceinline__ float bf16_to_f(unsigned short h) {
    return __uint_as_float(((unsigned int)h) << 16);
}
__device__ __forceinline__ uint4 pack8(const unsigned short* h) {
    uint4 u;
    u.x = (unsigned)h[0] | ((unsigned)h[1] << 16);
    u.y = (unsigned)h[2] | ((unsigned)h[3] << 16);
    u.z = (unsigned)h[4] | ((unsigned)h[5] << 16);
    u.w = (unsigned)h[6] | ((unsigned)h[7] << 16);
    return u;
}

__global__ void c2_kernel(const float* __restrict__ lut, float* __restrict__ ws) {
    if (threadIdx.x == 0) ((int*)ws)[WS_CNT_I] = 0;
    int t = threadIdx.x;
    for (int k = t; k < 512; k += 256) {
        const float4* row = (const float4*)(lut + (size_t)k * DIM);
        float s = 0.f;
        #pragma unroll 8
        for (int i = 0; i < DIM / 4; ++i) {
            float4 v = row[i];
            s += v.x * v.x + v.y * v.y + v.z * v.z + v.w * v.w;
        }
        ws[k] = s;
    }
}

// lut -> bf16 hi/lo, fragment-linear: chunk((dc*32+ctu)*2+lvl) of 1KB, lane*16B inside
__global__ void lutprep_kernel(const float* __restrict__ lut, float* __restrict__ ws) {
    int g = blockIdx.x * 256 + threadIdx.x;    // 0..16383
    int lane = g & 63;
    int ctu  = (g >> 6) & 31;
    int dcg  = g >> 11;
    int code = ctu * 16 + (lane & 15);
    int d0   = dcg * 32 + (lane >> 4) * 8;
    const float* src = lut + (size_t)code * DIM + d0;
    unsigned short hi[8], lo[8];
    #pragma unroll
    for (int j = 0; j < 8; ++j) {
        float v = src[j];
        unsigned short h = bf16_rne(v);
        hi[j] = h;
        lo[j] = bf16_rne(v - bf16_to_f(h));
    }
    char* dst = (char*)ws + WS_LUTBF_B + (size_t)((dcg * 32 + ctu) * 2) * 1024 + lane * 16;
    *(uint4*)dst          = pack8(hi);
    *(uint4*)(dst + 1024) = pack8(lo);
}

__global__ __launch_bounds__(NT, 2) void vq_kernel(const float* __restrict__ x,
                                                   const float* __restrict__ lut,
                                                   float* __restrict__ out,
                                                   float* __restrict__ ws) {
    extern __shared__ char smem[];
    // [0,65536): A chunks ((rt*8+dc)*2+lvl)*1024 + lane*16
    float* redv1 = (float*)(smem + 65536);   // [4cg][64row]
    float* redv2 = (float*)(smem + 66560);
    int*   redi1 = (int*)(smem + 67584);
    int*   qsh   = (int*)(smem + 68608);
    float* wsumx = (float*)(smem + 68864);

    const char* lutbf = (const char*)ws + WS_LUTBF_B;

    const int tid = threadIdx.x;
    const int blk = blockIdx.x;
    const int n0  = blk * QBM;
    const int b   = n0 >> 10;
    const int hw0 = n0 & 1023;
    const float* xb = x + (size_t)b * (DIM * HW) + hw0;

    const int wave = tid >> 6;   // = cg, code quarter
    const int lane = tid & 63;
    const int l15  = lane & 15;
    const int l4   = lane >> 4;
    const int cg   = wave;

    float c2reg[2][4];
    #pragma unroll
    for (int ctg = 0; ctg < 2; ++ctg)
        #pragma unroll
        for (int ct = 0; ct < 4; ++ct)
            c2reg[ctg][ct] = ws[(cg * 8 + ctg * 4 + ct) * 16 + l15];

    // ---- stage A ONCE: 64 rows x 256 d, hi/lo ----
    const int srow = tid & 63;
    const int sdg  = tid >> 6;           // d-base = sdg*64
    float x2local = 0.f;
    #pragma unroll
    for (int jj = 0; jj < 8; ++jj) {
        const int d0 = sdg * 64 + jj * 8;
        unsigned short hi[8], lo[8];
        #pragma unroll
        for (int e = 0; e < 8; ++e) {
            float v = xb[(size_t)(d0 + e) * HW + srow];
            x2local = fmaf(v, v, x2local);
            unsigned short h = bf16_rne(v);
            hi[e] = h;
            lo[e] = bf16_rne(v - bf16_to_f(h));
        }
        const int dc = d0 >> 5, doct = (d0 >> 3) & 3, rt = srow >> 4;
        char* basep = smem + (size_t)((rt * 8 + dc) * 2) * 1024 + (doct * 16 + (srow & 15)) * 16;
        *(uint4*)basep          = pack8(hi);
        *(uint4*)(basep + 1024) = pack8(lo);
    }
    __syncthreads();   // the ONLY barrier before the K loop

    // ---- barrier-free K loop: wave cg streams codes [cg*128, cg*128+128) ----
    for (int ctg = 0; ctg < 2; ++ctg) {
        const int ctu0 = cg * 8 + ctg * 4;
        floatx4 acc[4][4];
        #pragma unroll
        for (int i = 0; i < 4; ++i)
            #pragma unroll
            for (int j = 0; j < 4; ++j) acc[i][j] = (floatx4)0.f;

        short8v bh0[4], bl0[4], bh1[4], bl1[4];
        #pragma unroll
        for (int ct = 0; ct < 4; ++ct) {
            const char* bp = lutbf + (size_t)((ctu0 + ct) * 2) * 1024 + lane * 16;
            bh0[ct] = *(const short8v*)bp;
            bl0[ct] = *(const short8v*)(bp + 1024);
        }
        #pragma unroll
        for (int dc = 0; dc < 8; ++dc) {
            if (dc < 7) {   // prefetch B[dc+1] into the other reg buffer (counted vmcnt)
                #pragma unroll
                for (int ct = 0; ct < 4; ++ct) {
                    const char* bp = lutbf + (size_t)(((dc + 1) * 32 + ctu0 + ct) * 2) * 1024 + lane * 16;
                    if ((dc & 1) == 0) { bh1[ct] = *(const short8v*)bp; bl1[ct] = *(const short8v*)(bp + 1024); }
                    else               { bh0[ct] = *(const short8v*)bp; bl0[ct] = *(const short8v*)(bp + 1024); }
                }
            }
            short8v ah[4], al[4];
            #pragma unroll
            for (int rtl = 0; rtl < 4; ++rtl) {
                const char* ra = smem + (size_t)((rtl * 8 + dc) * 2) * 1024 + lane * 16;
                ah[rtl] = *(const short8v*)ra;
                al[rtl] = *(const short8v*)(ra + 1024);
            }
            // per-acc order per dc: hh, lh, hl (matches R8-R11 passing kernels)
            #pragma unroll
            for (int ct = 0; ct < 4; ++ct) {
                short8v bh = (dc & 1) ? bh1[ct] : bh0[ct];
                #pragma unroll
                for (int rtl = 0; rtl < 4; ++rtl)
                    acc[rtl][ct] = __builtin_amdgcn_mfma_f32_16x16x32_bf16(ah[rtl], bh, acc[rtl][ct], 0, 0, 0);
            }
            #pragma unroll
            for (int ct = 0; ct < 4; ++ct) {
                short8v bh = (dc & 1) ? bh1[ct] : bh0[ct];
                #pragma unroll
                for (int rtl = 0; rtl < 4; ++rtl)
                    acc[rtl][ct] = __builtin_amdgcn_mfma_f32_16x16x32_bf16(al[rtl], bh, acc[rtl][ct], 0, 0, 0);
            }
            #pragma unroll
            for (int ct = 0; ct < 4; ++ct) {
                short8v bl = (dc & 1) ? bl1[ct] : bl0[ct];
                #pragma unroll
                for (int rtl = 0; rtl < 4; ++rtl)
                    acc[rtl][ct] = __builtin_amdgcn_mfma_f32_16x16x32_bf16(ah[rtl], bl, acc[rtl][ct], 0, 0, 0);
            }
        }
        // ---- fold this ctg into LDS running best (per-wave rows, no race) ----
        #pragma unroll
        for (int rtl = 0; rtl < 4; ++rtl) {
            #pragma unroll
            for (int r = 0; r < 4; ++r) {
                float v1 = 3.4e38f, v2 = 3.4e38f; int i1 = 0;
                #pragma unroll
                for (int ct = 0; ct < 4; ++ct) {
                    int code = (ctu0 + ct) * 16 + l15;
                    float dist = fmaf(-2.f, acc[rtl][ct][r], c2reg[ctg][ct]);
                    if (dist < v1) { v2 = v1; v1 = dist; i1 = code; }
                    else if (dist < v2) v2 = dist;
                }
                #pragma unroll
                for (int off = 1; off < 16; off <<= 1) {
                    float ov1 = __shfl_xor(v1, off, 64);
                    int   oi1 = __shfl_xor(i1, off, 64);
                    float ov2 = __shfl_xor(v2, off, 64);
                    float nv2 = fminf(fmaxf(v1, ov1), fminf(v2, ov2));
                    if (ov1 < v1 || (ov1 == v1 && oi1 < i1)) { v1 = ov1; i1 = oi1; }
                    v2 = nv2;
                }
                if (l15 == 0) {
                    int idx = cg * 64 + rtl * 16 + l4 * 4 + r;
                    if (ctg == 0) {
                        redv1[idx] = v1; redi1[idx] = i1; redv2[idx] = v2;
                    } else {
                        float ov1 = redv1[idx]; float ov2 = redv2[idx];
                        float nv2 = fminf(fmaxf(v1, ov1), fminf(v2, ov2));
                        if (v1 < ov1) { redv1[idx] = v1; redi1[idx] = i1; }  // tie keeps lower code (stored)
                        redv2[idx] = nv2;
                    }
                }
            }
        }
    }
    __syncthreads();   // red arrays final

    float dist_part = 0.f;
    if (tid < QBM) {
        const int row = tid;
        float v1 = redv1[row]; int i1 = redi1[row]; float v2 = redv2[row];
        #pragma unroll
        for (int s = 1; s < 4; ++s) {
            float ov1 = redv1[s * 64 + row]; int oi1 = redi1[s * 64 + row]; float ov2 = redv2[s * 64 + row];
            float nv2 = fminf(fmaxf(v1, ov1), fminf(v2, ov2));
            if (ov1 < v1 || (ov1 == v1 && oi1 < i1)) { v1 = ov1; i1 = oi1; }
            v2 = nv2;
        }
        qsh[row] = i1;
        out[OUT_Q_OFF + n0 + row] = (float)i1;
        if (v2 - v1 <= MARGIN) {
            int idx = atomicAdd((int*)ws + WS_CNT_I, 1);
            ((int*)ws)[WS_LIST_I + idx] = n0 + row;
        }
        dist_part = v1;
    }
    float dv = dist_part;
    #pragma unroll
    for (int off = 32; off; off >>= 1) dv += __shfl_down(dv, off, 64);
    if (tid == 0) ws[WS_DIST + blk] = dv;

    float xv = x2local;
    #pragma unroll
    for (int off = 32; off; off >>= 1) xv += __shfl_down(xv, off, 64);
    if (lane == 0) wsumx[wave] = xv;
    __syncthreads();   // qsh + wsumx ready
    if (tid == 0) ws[WS_X2 + blk] = wsumx[0] + wsumx[1] + wsumx[2] + wsumx[3];

    // ---- x_e write (approx q; exact pass fixes flagged rows) ----
    {
        const int row = tid & 63;
        const int dg  = tid >> 6;
        const int q   = qsh[row];
        const float* crow = lut + (size_t)q * DIM;
        float* ob = out + (size_t)b * (DIM * HW) + hw0 + row;
        #pragma unroll 4
        for (int i = 0; i < 16; ++i) {
            int d0 = dg * 64 + i * 4;
            float4 c = *(const float4*)(crow + d0);
            ob[(size_t)(d0 + 0) * HW] = c.x;
            ob[(size_t)(d0 + 1) * HW] = c.y;
            ob[(size_t)(d0 + 2) * HW] = c.z;
            ob[(size_t)(d0 + 3) * HW] = c.w;
        }
    }
}

// exact fp32 recheck of flagged rows (sequential-fmaf form, matches np-passing R6-R11)
__global__ void exact_kernel(const float* __restrict__ x, const float* __restrict__ lut,
                             float* __restrict__ out, const float* __restrict__ ws) {
    __shared__ float xr[DIM];
    __shared__ float rv[256];
    __shared__ int   ri[256];
    const int cnt = ((const int*)ws)[WS_CNT_I];
    const int* list = (const int*)ws + WS_LIST_I;
    const int tid = threadIdx.x;
    for (int ii = blockIdx.x; ii < cnt; ii += gridDim.x) {
        const int row = list[ii];
        const int b = row >> 10, hw = row & 1023;
        __syncthreads();
        xr[tid] = x[(size_t)b * (DIM * HW) + (size_t)tid * HW + hw];
        __syncthreads();
        float bv = 3.4e38f; int bi = 0;
        #pragma unroll
        for (int k2 = 0; k2 < 2; ++k2) {
            int k = tid + k2 * 256;
            const float* cr = lut + (size_t)k * DIM;
            float dot = 0.f;
            for (int d = 0; d < DIM; ++d) dot = fmaf(xr[d], cr[d], dot);
            float dist = fmaf(-2.f, dot, ws[k]);
            if (dist < bv || (dist == bv && k < bi)) { bv = dist; bi = k; }
        }
        rv[tid] = bv; ri[tid] = bi;
        __syncthreads();
        for (int s = 128; s; s >>= 1) {
            if (tid < s) {
                float ov = rv[tid + s]; int oi = ri[tid + s];
                if (ov < rv[tid] || (ov == rv[tid] && oi < ri[tid])) {
                    rv[tid] = ov; ri[tid] = oi;
                }
            }
            __syncthreads();
        }
        const int q = ri[0];
        if (tid == 0) out[OUT_Q_OFF + row] = (float)q;
        out[(size_t)b * (DIM * HW) + (size_t)tid * HW + hw] = lut[(size_t)q * DIM + tid];
    }
}

__global__ void loss_kernel(float* __restrict__ out, const float* __restrict__ ws) {
    __shared__ float wsum[4];
    int tid = threadIdx.x;
    float s = 0.f;
    for (int i = tid; i < 2048; i += 256) s += ws[WS_DIST + i];   // dist[512,1536) + x2[1536,2560)
    #pragma unroll
    for (int off = 32; off; off >>= 1) s += __shfl_down(s, off, 64);
    if ((tid & 63) == 0) wsum[tid >> 6] = s;
    __syncthreads();
    if (tid == 0) {
        float total = wsum[0] + wsum[1] + wsum[2] + wsum[3];
        out[OUT_LOSS_OFF] = total * (1.25f / 16777216.f);
    }
}

extern "C" void kernel_launch(void* const* d_in, const int* in_sizes, int n_in,
                              void* d_out, int out_size, void* d_ws, size_t ws_size,
                              hipStream_t stream) {
    const float* x   = (const float*)d_in[0];
    const float* lut = (const float*)d_in[1];
    float* out = (float*)d_out;
    float* ws  = (float*)d_ws;

    (void)hipFuncSetAttribute((const void*)vq_kernel,
                              hipFuncAttributeMaxDynamicSharedMemorySize, VQ_LDS);

    c2_kernel<<<1, 256, 0, stream>>>(lut, ws);
    lutprep_kernel<<<64, 256, 0, stream>>>(lut, ws);
    vq_kernel<<<NBLK, NT, VQ_LDS, stream>>>(x, lut, out, ws);
    exact_kernel<<<1024, 256, 0, stream>>>(x, lut, out, ws);
    loss_kernel<<<1, 256, 0, stream>>>(out, ws);
}

// Round 13
// 145.154 us; speedup vs baseline: 2.0321x; 2.0321x over previous
//
#include <hip/hip_runtime.h>

#define DIM     256
#define HW      1024
#define N_ROWS  65536
#define NT      256
#define QBM     64
#define NBLK    1024
#define MARGIN  0.0625f

#define OUT_Q_OFF    16777216
#define OUT_LOSS_OFF 16842752

// ws: floats [0,512) c2 ; [512,1536) dist partials ; [1536,2560) x2 partials
// int [3072] flag count ; ints [4096, 69632) flagged-row list
// bytes [524288, 1048576) lut bf16 hi/lo fragment-linear
#define WS_DIST   512
#define WS_X2     1536
#define WS_CNT_I  3072
#define WS_LIST_I 4096
#define WS_LUTBF_B 524288

#define VQ_LDS 73728   // 64KB B + 8KB A

typedef __attribute__((ext_vector_type(8))) short short8v;
typedef __attribute__((ext_vector_type(4))) float floatx4;

#define GLOAD_LDS16(gaddr, laddr) \
    __builtin_amdgcn_global_load_lds((const __attribute__((address_space(1))) unsigned int*)(gaddr), \
                                     (__attribute__((address_space(3))) unsigned int*)(laddr), 16, 0, 0)

__device__ __forceinline__ unsigned short bf16_rne(float f) {
    unsigned int u = __float_as_uint(f);
    u += 0x7fffu + ((u >> 16) & 1u);
    return (unsigned short)(u >> 16);
}
__device__ __forceinline__ float bf16_to_f(unsigned short h) {
    return __uint_as_float(((unsigned int)h) << 16);
}
__device__ __forceinline__ uint4 pack8(const unsigned short* h) {
    uint4 u;
    u.x = (unsigned)h[0] | ((unsigned)h[1] << 16);
    u.y = (unsigned)h[2] | ((unsigned)h[3] << 16);
    u.z = (unsigned)h[4] | ((unsigned)h[5] << 16);
    u.w = (unsigned)h[6] | ((unsigned)h[7] << 16);
    return u;
}

__global__ void c2_kernel(const float* __restrict__ lut, float* __restrict__ ws) {
    if (threadIdx.x == 0) ((int*)ws)[WS_CNT_I] = 0;
    int t = threadIdx.x;
    for (int k = t; k < 512; k += 256) {
        const float4* row = (const float4*)(lut + (size_t)k * DIM);
        float s = 0.f;
        #pragma unroll 8
        for (int i = 0; i < DIM / 4; ++i) {
            float4 v = row[i];
            s += v.x * v.x + v.y * v.y + v.z * v.z + v.w * v.w;
        }
        ws[k] = s;
    }
}

// lut -> bf16 hi/lo, fragment-linear: chunk((dc*32+ctu)*2+lvl)*1KB + lane*16B
__global__ void lutprep_kernel(const float* __restrict__ lut, float* __restrict__ ws) {
    int g = blockIdx.x * 256 + threadIdx.x;    // 0..16383
    int lane = g & 63;
    int ctu  = (g >> 6) & 31;
    int dcg  = g >> 11;
    int code = ctu * 16 + (lane & 15);
    int d0   = dcg * 32 + (lane >> 4) * 8;
    const float* src = lut + (size_t)code * DIM + d0;
    unsigned short hi[8], lo[8];
    #pragma unroll
    for (int j = 0; j < 8; ++j) {
        float v = src[j];
        unsigned short h = bf16_rne(v);
        hi[j] = h;
        lo[j] = bf16_rne(v - bf16_to_f(h));
    }
    char* dst = (char*)ws + WS_LUTBF_B + (size_t)((dcg * 32 + ctu) * 2) * 1024 + lane * 16;
    *(uint4*)dst          = pack8(hi);
    *(uint4*)(dst + 1024) = pack8(lo);
}

__global__ __launch_bounds__(NT, 2) void vq_kernel(const float* __restrict__ x,
                                                   const float* __restrict__ lut,
                                                   float* __restrict__ out,
                                                   float* __restrict__ ws) {
    extern __shared__ char smem[];
    // smem[0,65536): B buffer, 64 chunks (ctu*2+lvl)*1024 + lane*16
    // smem[65536,73728): A buffer, chunks rt*2048 + lvl*1024 + lane*16

    const char* lutbf = (const char*)ws + WS_LUTBF_B;

    const int tid = threadIdx.x;
    const int blk = blockIdx.x;
    const int n0  = blk * QBM;
    const int b   = n0 >> 10;
    const int hw0 = n0 & 1023;
    const float* xb = x + (size_t)b * (DIM * HW) + hw0;

    const int wave = tid >> 6;   // = cg code quarter
    const int lane = tid & 63;
    const int l15  = lane & 15;
    const int l4   = lane >> 4;
    const int cg   = wave;

    // staging map (one slot per thread): rt = tid>>6, row = rt*16+l15, d-oct = l4
    const int srt  = tid >> 6;
    char* awr_hi = smem + 65536 + srt * 2048 + lane * 16;
    const int arow = srt * 16 + l15;
    const int ad0  = l4 * 8;

    float x2local = 0.f;
    floatx4 acc[4][8];
    #pragma unroll
    for (int i = 0; i < 4; ++i)
        #pragma unroll
        for (int j = 0; j < 8; ++j) acc[i][j] = (floatx4)0.f;

    // ---- prologue: DMA B[0], stage A[0] ----
    {
        #pragma unroll
        for (int i = 0; i < 16; ++i) {
            int cc = (tid >> 6) * 16 + i;
            GLOAD_LDS16(lutbf + (size_t)(0 * 64 + cc) * 1024 + lane * 16, smem + cc * 1024);
        }
        const float* src = xb + (size_t)ad0 * HW + arow;
        unsigned short hi[8], lo[8];
        #pragma unroll
        for (int e = 0; e < 8; ++e) {
            float v = src[(size_t)e * HW];
            x2local = fmaf(v, v, x2local);
            unsigned short h = bf16_rne(v);
            hi[e] = h;
            lo[e] = bf16_rne(v - bf16_to_f(h));
        }
        *(uint4*)awr_hi          = pack8(hi);
        *(uint4*)(awr_hi + 1024) = pack8(lo);
    }
    __syncthreads();

    for (int dc = 0; dc < 8; ++dc) {
        // ---- read ALL frags to registers ----
        short8v ah[4], al[4];
        #pragma unroll
        for (int rtl = 0; rtl < 4; ++rtl) {
            const char* ra = smem + 65536 + rtl * 2048 + lane * 16;
            ah[rtl] = *(const short8v*)ra;
            al[rtl] = *(const short8v*)(ra + 1024);
        }
        short8v bh[8], bl[8];
        #pragma unroll
        for (int ct = 0; ct < 8; ++ct) {
            const char* bp = smem + (size_t)((cg * 8 + ct) * 2) * 1024 + lane * 16;
            bh[ct] = *(const short8v*)bp;
            bl[ct] = *(const short8v*)(bp + 1024);
        }
        // ---- light barrier: my LDS reads done, then block-wide rendezvous (NO vmcnt drain) ----
        __builtin_amdgcn_sched_barrier(0);
        asm volatile("s_waitcnt lgkmcnt(0)" ::: "memory");
        __builtin_amdgcn_sched_barrier(0);
        __builtin_amdgcn_s_barrier();
        __builtin_amdgcn_sched_barrier(0);
        // ---- issue next-tile B DMA + x loads (span the MFMA phase) ----
        float xn[8];
        if (dc < 7) {
            #pragma unroll
            for (int i = 0; i < 16; ++i) {
                int cc = (tid >> 6) * 16 + i;
                GLOAD_LDS16(lutbf + (size_t)((dc + 1) * 64 + cc) * 1024 + lane * 16, smem + cc * 1024);
            }
            const float* src = xb + (size_t)((dc + 1) * 32 + ad0) * HW + arow;
            #pragma unroll
            for (int e = 0; e < 8; ++e) xn[e] = src[(size_t)e * HW];
        }
        // ---- MFMAs: per-acc order hh, lh, hl (bitwise-identical to R8-R11) ----
        __builtin_amdgcn_s_setprio(1);
        #pragma unroll
        for (int ct = 0; ct < 8; ++ct)
            #pragma unroll
            for (int rtl = 0; rtl < 4; ++rtl)
                acc[rtl][ct] = __builtin_amdgcn_mfma_f32_16x16x32_bf16(ah[rtl], bh[ct], acc[rtl][ct], 0, 0, 0);
        #pragma unroll
        for (int ct = 0; ct < 8; ++ct)
            #pragma unroll
            for (int rtl = 0; rtl < 4; ++rtl)
                acc[rtl][ct] = __builtin_amdgcn_mfma_f32_16x16x32_bf16(al[rtl], bh[ct], acc[rtl][ct], 0, 0, 0);
        #pragma unroll
        for (int ct = 0; ct < 8; ++ct)
            #pragma unroll
            for (int rtl = 0; rtl < 4; ++rtl)
                acc[rtl][ct] = __builtin_amdgcn_mfma_f32_16x16x32_bf16(ah[rtl], bl[ct], acc[rtl][ct], 0, 0, 0);
        __builtin_amdgcn_s_setprio(0);
        // ---- convert + stage A[dc+1] ----
        if (dc < 7) {
            unsigned short hi[8], lo[8];
            #pragma unroll
            for (int e = 0; e < 8; ++e) {
                float v = xn[e];
                x2local = fmaf(v, v, x2local);
                unsigned short h = bf16_rne(v);
                hi[e] = h;
                lo[e] = bf16_rne(v - bf16_to_f(h));
            }
            *(uint4*)awr_hi          = pack8(hi);
            *(uint4*)(awr_hi + 1024) = pack8(lo);
        }
        __syncthreads();   // full drain: B DMA landed + A writes visible
    }

    // overlays on B buffer (dead)
    float* redv1 = (float*)smem;            // [4][64]
    float* redv2 = (float*)(smem + 1024);
    int*   redi1 = (int*)(smem + 2048);
    int*   qsh   = (int*)(smem + 3072);
    float* wsumx = (float*)(smem + 3328);

    // ---- per-row best1/best2 within wave ----
    #pragma unroll
    for (int rtl = 0; rtl < 4; ++rtl) {
        #pragma unroll
        for (int r = 0; r < 4; ++r) {
            float v1 = 3.4e38f, v2 = 3.4e38f; int i1 = 0;
            #pragma unroll
            for (int ct = 0; ct < 8; ++ct) {
                int code = (cg * 8 + ct) * 16 + l15;
                float dist = fmaf(-2.f, acc[rtl][ct][r], ws[code]);
                if (dist < v1) { v2 = v1; v1 = dist; i1 = code; }
                else if (dist < v2) v2 = dist;
            }
            #pragma unroll
            for (int off = 1; off < 16; off <<= 1) {
                float ov1 = __shfl_xor(v1, off, 64);
                int   oi1 = __shfl_xor(i1, off, 64);
                float ov2 = __shfl_xor(v2, off, 64);
                float nv2 = fminf(fmaxf(v1, ov1), fminf(v2, ov2));
                if (ov1 < v1 || (ov1 == v1 && oi1 < i1)) { v1 = ov1; i1 = oi1; }
                v2 = nv2;
            }
            if (l15 == 0) {
                int idx = cg * 64 + rtl * 16 + l4 * 4 + r;
                redv1[idx] = v1; redi1[idx] = i1; redv2[idx] = v2;
            }
        }
    }
    __syncthreads();

    float dist_part = 0.f;
    if (tid < QBM) {
        const int row = tid;
        float v1 = redv1[row]; int i1 = redi1[row]; float v2 = redv2[row];
        #pragma unroll
        for (int s = 1; s < 4; ++s) {
            float ov1 = redv1[s * 64 + row]; int oi1 = redi1[s * 64 + row]; float ov2 = redv2[s * 64 + row];
            float nv2 = fminf(fmaxf(v1, ov1), fminf(v2, ov2));
            if (ov1 < v1 || (ov1 == v1 && oi1 < i1)) { v1 = ov1; i1 = oi1; }
            v2 = nv2;
        }
        qsh[row] = i1;
        out[OUT_Q_OFF + n0 + row] = (float)i1;
        if (v2 - v1 <= MARGIN) {
            int idx = atomicAdd((int*)ws + WS_CNT_I, 1);
            ((int*)ws)[WS_LIST_I + idx] = n0 + row;
        }
        dist_part = v1;
    }
    float dv = dist_part;
    #pragma unroll
    for (int off = 32; off; off >>= 1) dv += __shfl_down(dv, off, 64);
    if (tid == 0) ws[WS_DIST + blk] = dv;

    float xv = x2local;
    #pragma unroll
    for (int off = 32; off; off >>= 1) xv += __shfl_down(xv, off, 64);
    if (lane == 0) wsumx[wave] = xv;
    __syncthreads();
    if (tid == 0) ws[WS_X2 + blk] = wsumx[0] + wsumx[1] + wsumx[2] + wsumx[3];

    // ---- x_e write (approx q; exact pass fixes flagged rows) ----
    {
        const int row = tid & 63;
        const int dg  = tid >> 6;
        const int q   = qsh[row];
        const float* crow = lut + (size_t)q * DIM;
        float* ob = out + (size_t)b * (DIM * HW) + hw0 + row;
        #pragma unroll 4
        for (int i = 0; i < 16; ++i) {
            int d0 = dg * 64 + i * 4;
            float4 c = *(const float4*)(crow + d0);
            ob[(size_t)(d0 + 0) * HW] = c.x;
            ob[(size_t)(d0 + 1) * HW] = c.y;
            ob[(size_t)(d0 + 2) * HW] = c.z;
            ob[(size_t)(d0 + 3) * HW] = c.w;
        }
    }
}

// exact fp32 recheck of flagged rows (sequential-fmaf form, matches np-passing R6-R11)
__global__ void exact_kernel(const float* __restrict__ x, const float* __restrict__ lut,
                             float* __restrict__ out, const float* __restrict__ ws) {
    __shared__ float xr[DIM];
    __shared__ float rv[256];
    __shared__ int   ri[256];
    const int cnt = ((const int*)ws)[WS_CNT_I];
    const int* list = (const int*)ws + WS_LIST_I;
    const int tid = threadIdx.x;
    for (int ii = blockIdx.x; ii < cnt; ii += gridDim.x) {
        const int row = list[ii];
        const int b = row >> 10, hw = row & 1023;
        __syncthreads();
        xr[tid] = x[(size_t)b * (DIM * HW) + (size_t)tid * HW + hw];
        __syncthreads();
        float bv = 3.4e38f; int bi = 0;
        #pragma unroll
        for (int k2 = 0; k2 < 2; ++k2) {
            int k = tid + k2 * 256;
            const float* cr = lut + (size_t)k * DIM;
            float dot = 0.f;
            for (int d = 0; d < DIM; ++d) dot = fmaf(xr[d], cr[d], dot);
            float dist = fmaf(-2.f, dot, ws[k]);
            if (dist < bv || (dist == bv && k < bi)) { bv = dist; bi = k; }
        }
        rv[tid] = bv; ri[tid] = bi;
        __syncthreads();
        for (int s = 128; s; s >>= 1) {
            if (tid < s) {
                float ov = rv[tid + s]; int oi = ri[tid + s];
                if (ov < rv[tid] || (ov == rv[tid] && oi < ri[tid])) {
                    rv[tid] = ov; ri[tid] = oi;
                }
            }
            __syncthreads();
        }
        const int q = ri[0];
        if (tid == 0) out[OUT_Q_OFF + row] = (float)q;
        out[(size_t)b * (DIM * HW) + (size_t)tid * HW + hw] = lut[(size_t)q * DIM + tid];
    }
}

__global__ void loss_kernel(float* __restrict__ out, const float* __restrict__ ws) {
    __shared__ float wsum[4];
    int tid = threadIdx.x;
    float s = 0.f;
    for (int i = tid; i < 2048; i += 256) s += ws[WS_DIST + i];   // dist[512,1536) + x2[1536,2560)
    #pragma unroll
    for (int off = 32; off; off >>= 1) s += __shfl_down(s, off, 64);
    if ((tid & 63) == 0) wsum[tid >> 6] = s;
    __syncthreads();
    if (tid == 0) {
        float total = wsum[0] + wsum[1] + wsum[2] + wsum[3];
        out[OUT_LOSS_OFF] = total * (1.25f / 16777216.f);
    }
}

extern "C" void kernel_launch(void* const* d_in, const int* in_sizes, int n_in,
                              void* d_out, int out_size, void* d_ws, size_t ws_size,
                              hipStream_t stream) {
    const float* x   = (const float*)d_in[0];
    const float* lut = (const float*)d_in[1];
    float* out = (float*)d_out;
    float* ws  = (float*)d_ws;

    (void)hipFuncSetAttribute((const void*)vq_kernel,
                              hipFuncAttributeMaxDynamicSharedMemorySize, VQ_LDS);

    c2_kernel<<<1, 256, 0, stream>>>(lut, ws);
    lutprep_kernel<<<64, 256, 0, stream>>>(lut, ws);
    vq_kernel<<<NBLK, NT, VQ_LDS, stream>>>(x, lut, out, ws);
    exact_kernel<<<1024, 256, 0, stream>>>(x, lut, out, ws);
    loss_kernel<<<1, 256, 0, stream>>>(out, ws);
}